// Round 8
// baseline (183.236 us; speedup 1.0000x reference)
//
#include <hip/hip_runtime.h>

#define NH 8
#define HD 32
#define SUMP 16
#define LQ 4096
#define BS 4
#define LV 8500
#define NQ (BS * LQ)   // 16384
#define MV (BS * LV)   // 34000

typedef float f32x4 __attribute__((ext_vector_type(4)));
typedef _Float16 f16x8 __attribute__((ext_vector_type(8)));
typedef _Float16 f16x2 __attribute__((ext_vector_type(2)));

// ---------- prep: weights -> fp16 fragment-linear; bias concat ----------
// frag-linear: unit block (T = n>>4, C = k>>5) of 512 fp16 at offset (T*8+C)*512;
// within: lane16 = (n&15) + 16*((k>>3)&3) at lane16*8, elem = k&7.
__global__ __launch_bounds__(256) void prep_kernel(
    const float* __restrict__ Wv, const float* __restrict__ Woff,
    const float* __restrict__ Wattn, const float* __restrict__ Wo,
    const float* __restrict__ boff, const float* __restrict__ battn,
    _Float16* __restrict__ WtVf, _Float16* __restrict__ WtOAf,
    _Float16* __restrict__ WtOf, float* __restrict__ biasOA)
{
    int g = blockIdx.x * 256 + threadIdx.x;    // 0..229375
    int gl; _Float16* dst; int which;
    if (g < 65536)       { gl = g;          dst = WtVf;  which = 0; }
    else if (g < 163840) { gl = g - 65536;  dst = WtOAf; which = 1; }
    else                 { gl = g - 163840; dst = WtOf;  which = 2; }
    int e = gl & 7, m16 = (gl >> 3) & 15, q = (gl >> 7) & 3, C = (gl >> 9) & 7, T = gl >> 12;
    int n = T * 16 + m16, k = C * 32 + q * 8 + e;
    float w;
    if (which == 0)      w = Wv[k * 256 + n];
    else if (which == 1) w = (n < 256) ? Woff[k * 256 + n] : Wattn[k * 128 + (n - 256)];
    else                 w = Wo[k * 256 + n];
    dst[gl] = (_Float16)w;
    if (blockIdx.x == 0) biasOA[threadIdx.x] = boff[threadIdx.x];
    if (blockIdx.x == 1 && threadIdx.x < 128) biasOA[256 + threadIdx.x] = battn[threadIdx.x];
}

__device__ __forceinline__ f16x8 cvt8(const float4& lo, const float4& hi) {
    f16x8 r;
    r[0] = (_Float16)lo.x; r[1] = (_Float16)lo.y; r[2] = (_Float16)lo.z; r[3] = (_Float16)lo.w;
    r[4] = (_Float16)hi.x; r[5] = (_Float16)hi.y; r[6] = (_Float16)hi.z; r[7] = (_Float16)hi.w;
    return r;
}

// ---------- single-barrier chunk GEMM (R6 config: 64-row blocks) ----------
// Block = 64 A-rows x (4*NI*16) cols, K=256. Stage ALL of A (64x256) into LDS fp16
// ONCE (16 dwordx4/thread, cvt in reg, XOR-swizzled ds_write_b128), ONE
// __syncthreads(), then 8 K-steps of ds_read_b128 + frag-linear global B (L2-hot)
// + MFMA with NO barriers -> waves free-run, no per-K-step vmcnt(0) drain.
// Swizzle: 16B-slot' = slot ^ (row&7). Read quarter (=quad) has 16 lanes over 8
// slots -> 2-way (free, m136); write quarter 16 distinct slots -> conflict-free.
// SOFTMAX (OA only): logit tiles (ntile>=16) have l16 = p for fixed (row,h) ->
// softmax over the native 16-lane shfl group IN the epilogue; oa then stores
// post-softmax weights (same fp32 math + rcpf as sample's old Phase A;
// bit-identical), removing the softmax chain from sample entirely.
template <int NI, bool V_MODE, bool A_F16, bool SOFTMAX>
__device__ __forceinline__ void chunk_gemm(
    const float* __restrict__ A32, const _Float16* __restrict__ A16,
    const _Float16* __restrict__ Bf, const float* __restrict__ bias,
    void* __restrict__ Cv, int M, int N, int mchunk, int ntbase,
    _Float16* __restrict__ As /* 64*256 fp16 = 32KB */)
{
    const int t = threadIdx.x;
    const int wave = t >> 6, lane = t & 63;
    const int quad = lane >> 4, l16 = lane & 15;

    // ---- stage A: 64 rows x 256 k ----
    {
        const int srow = t >> 2, schunk = t & 3;   // 4 threads/row, 64 floats each
        int gr = mchunk * 64 + srow;
        if (gr > M - 1) gr = M - 1;
        if (A_F16) {
            const _Float16* src = A16 + (size_t)gr * 256 + schunk * 64;
            f16x8 hb[8];
            #pragma unroll
            for (int j = 0; j < 8; ++j) hb[j] = *(const f16x8*)(src + j * 8);
            #pragma unroll
            for (int j = 0; j < 8; ++j) {
                int slot = (schunk * 8 + j) ^ (srow & 7);
                *(f16x8*)(As + srow * 256 + slot * 8) = hb[j];
            }
        } else {
            const float* src = A32 + (size_t)gr * 256 + schunk * 64;
            float4 buf[16];
            #pragma unroll
            for (int j = 0; j < 16; ++j) buf[j] = *(const float4*)(src + j * 4);
            #pragma unroll
            for (int j = 0; j < 8; ++j) {
                f16x8 h = cvt8(buf[2 * j], buf[2 * j + 1]);
                int slot = (schunk * 8 + j) ^ (srow & 7);
                *(f16x8*)(As + srow * 256 + slot * 8) = h;
            }
        }
    }
    __syncthreads();

    // ---- main loop: barrier-free ----
    const int ntile0 = ntbase + wave * NI;
    const _Float16* bp[NI];
    #pragma unroll
    for (int ni = 0; ni < NI; ++ni)
        bp[ni] = Bf + (size_t)(ntile0 + ni) * 4096 + lane * 8;

    f16x8 bcur[NI], bnxt[NI];
    f32x4 acc[4][NI] = {};
    #pragma unroll
    for (int ni = 0; ni < NI; ++ni) bcur[ni] = *(const f16x8*)(bp[ni]);

    #pragma unroll
    for (int k = 0; k < 8; ++k) {
        if (k < 7) {
            #pragma unroll
            for (int ni = 0; ni < NI; ++ni) bnxt[ni] = *(const f16x8*)(bp[ni] + (k + 1) * 512);
        }
        f16x8 af[4];
        #pragma unroll
        for (int mi = 0; mi < 4; ++mi) {
            int row = mi * 16 + l16;
            int slot = (quad + k * 4) ^ (row & 7);
            af[mi] = *(const f16x8*)(As + row * 256 + slot * 8);
        }
        #pragma unroll
        for (int mi = 0; mi < 4; ++mi)
            #pragma unroll
            for (int ni = 0; ni < NI; ++ni)
                acc[mi][ni] = __builtin_amdgcn_mfma_f32_16x16x32_f16(af[mi], bcur[ni], acc[mi][ni], 0, 0, 0);
        if (k < 7) {
            #pragma unroll
            for (int ni = 0; ni < NI; ++ni) bcur[ni] = bnxt[ni];
        }
    }

    // ---- epilogue: C/D col = l16, row = quad*4+r ----
    if (V_MODE) {
        #pragma unroll
        for (int mi = 0; mi < 4; ++mi) {
            int mq = mchunk * 64 + mi * 16 + quad * 4;
            size_t rb[4]; int vld[4];
            #pragma unroll
            for (int r = 0; r < 4; ++r) {
                int m = mq + r;
                vld[r] = (m < M);
                int mm = vld[r] ? m : 0;
                int b = mm / LV; int pos = mm - b * LV;
                rb[r] = ((size_t)b * NH * LV + pos) * 32;
            }
            #pragma unroll
            for (int ni = 0; ni < NI; ++ni) {
                int n = (ntile0 + ni) * 16 + l16;
                float bv = bias[n];
                int h = n >> 5, d = n & 31;
                size_t ho = (size_t)h * (LV * 32) + d;
                #pragma unroll
                for (int r = 0; r < 4; ++r)
                    if (vld[r]) ((_Float16*)Cv)[rb[r] + ho] = (_Float16)(acc[mi][ni][r] + bv);
            }
        }
    } else {
        #pragma unroll
        for (int ni = 0; ni < NI; ++ni) {
            int ntile = ntile0 + ni;
            int n = ntile * 16 + l16;
            float bv = bias[n];
            #pragma unroll
            for (int mi = 0; mi < 4; ++mi) {
                int mq = mchunk * 64 + mi * 16 + quad * 4;
                #pragma unroll
                for (int r = 0; r < 4; ++r) {
                    float x = acc[mi][ni][r] + bv;
                    if (SOFTMAX && ntile >= 16) {
                        // logit tile: l16 = p, fixed (row mq+r, h = ntile-16)
                        float mx = x;
                        #pragma unroll
                        for (int d = 8; d >= 1; d >>= 1) mx = fmaxf(mx, __shfl_xor(mx, d, 16));
                        float ex = __expf(x - mx);
                        float sm = ex;
                        #pragma unroll
                        for (int d = 8; d >= 1; d >>= 1) sm += __shfl_xor(sm, d, 16);
                        x = ex * __builtin_amdgcn_rcpf(sm);
                    }
                    ((float*)Cv)[(size_t)(mq + r) * N + n] = x;
                }
            }
        }
    }
}

// V: 532 m-chunks(64), full N=256 per block (NI=4) -> A fetched once.
// OA: 256 m-chunks(64) x 2 n-chunks (NI=3, 192 cols/block); chunk1 holds all
// logit tiles (16..23) -> softmax applied in epilogue.
__global__ __launch_bounds__(256) void gemm_dual_kernel(
    const float* __restrict__ value, const _Float16* __restrict__ WtVf,
    const float* __restrict__ b_v, _Float16* __restrict__ v_f16,
    const float* __restrict__ query, const _Float16* __restrict__ WtOAf,
    const float* __restrict__ biasOA, float* __restrict__ oa)
{
    __shared__ __align__(16) _Float16 As[64 * 256];
    int bid = blockIdx.x;
    if (bid < 532) {
        chunk_gemm<4, true, false, false>(value, nullptr, WtVf, b_v, v_f16, MV, 256,
                                          bid, 0, As);
    } else {
        int g = bid - 532;                 // 0..511
        chunk_gemm<3, false, false, true>(query, nullptr, WtOAf, biasOA, oa, NQ, 384,
                                          g >> 1, (g & 1) * 12, As);
    }
}

// ---------- O GEMM: 32x128 blocks (R6 config, 1024 blocks, 16 waves/CU) ----------
__global__ __launch_bounds__(256) void gemm_o_kernel(
    const _Float16* __restrict__ mid, const _Float16* __restrict__ WtOf,
    const float* __restrict__ b_o, float* __restrict__ out)
{
    __shared__ __align__(16) _Float16 As[32 * 256];   // 16 KB
    const int t = threadIdx.x;
    const int wave = t >> 6, lane = t & 63;
    const int quad = lane >> 4, l16 = lane & 15;
    const int mchunk = blockIdx.x >> 1;               // 0..511 (32 rows each)
    const int nc = blockIdx.x & 1;                    // 0..1 (128 cols each)

    // stage A: 32 rows x 256 fp16; 8 threads/row (32 fp16 = 4 swizzled slots)
    {
        const int srow = t >> 3, sc = t & 7;
        const _Float16* src = mid + (size_t)(mchunk * 32 + srow) * 256 + sc * 32;
        f16x8 hb[4];
        #pragma unroll
        for (int j = 0; j < 4; ++j) hb[j] = *(const f16x8*)(src + j * 8);
        #pragma unroll
        for (int j = 0; j < 4; ++j) {
            int slot = (sc * 4 + j) ^ (srow & 7);
            *(f16x8*)(As + srow * 256 + slot * 8) = hb[j];
        }
    }
    __syncthreads();

    const int wrow = wave >> 1, wcol = wave & 1;
    const int ntile0 = nc * 8 + wcol * 4;
    const _Float16* bp[4];
    #pragma unroll
    for (int ni = 0; ni < 4; ++ni)
        bp[ni] = WtOf + (size_t)(ntile0 + ni) * 4096 + lane * 8;

    f16x8 bcur[4], bnxt[4];
    f32x4 acc[4] = {};
    #pragma unroll
    for (int ni = 0; ni < 4; ++ni) bcur[ni] = *(const f16x8*)(bp[ni]);

    #pragma unroll
    for (int k = 0; k < 8; ++k) {
        if (k < 7) {
            #pragma unroll
            for (int ni = 0; ni < 4; ++ni) bnxt[ni] = *(const f16x8*)(bp[ni] + (k + 1) * 512);
        }
        const int row = wrow * 16 + l16;
        const int slot = (quad + k * 4) ^ (row & 7);
        f16x8 af = *(const f16x8*)(As + row * 256 + slot * 8);
        #pragma unroll
        for (int ni = 0; ni < 4; ++ni)
            acc[ni] = __builtin_amdgcn_mfma_f32_16x16x32_f16(af, bcur[ni], acc[ni], 0, 0, 0);
        if (k < 7) {
            #pragma unroll
            for (int ni = 0; ni < 4; ++ni) bcur[ni] = bnxt[ni];
        }
    }

    #pragma unroll
    for (int ni = 0; ni < 4; ++ni) {
        int n = (ntile0 + ni) * 16 + l16;
        float bv = b_o[n];
        int mq = mchunk * 32 + wrow * 16 + quad * 4;
        #pragma unroll
        for (int r = 0; r < 4; ++r)
            out[(size_t)(mq + r) * 256 + n] = acc[ni][r] + bv;
    }
}

// ---------- sampling: (b,h)-specialized blocks, XCD-pinned v-slices ----------
// Block = ONE (b,h) x 16 queries. xcd = blk&7 -> each XCD serves 4 fixed (b,h)
// combos; per-XCD v working set 2.2MB < 4MB L2.
// Phase A: thread t <-> (task = t>>4, p = t&15); logits arrive PRE-SOFTMAXED
// (OA epilogue) -> no shfl/exp chain here; corner weights packed to f16x2
// pairs. Phase B: level-balanced p = jj*4 + wp*2 + pgl; 16 hoisted 16B
// gathers; dot2 MAC (2 packs + 2 dot2 per (c,jj)).
__global__ void sample_kernel(
    const _Float16* __restrict__ v,          // [b][h][LV][32] fp16
    const float* __restrict__ oa,            // [NQ][384]: 0..255 offsets, 256..383 softmax w
    const float* __restrict__ refp,          // [NQ][4]
    _Float16* __restrict__ mid)              // [NQ][256] fp16
{
    const int blk = blockIdx.x;
    const int xcd = blk & 7, j = blk >> 3;
    const int bh = xcd * 4 + (j & 3);        // 0..31
    const int chunk = j >> 2;                // 0..255
    const int b = bh >> 3, h = bh & 7;
    const int rowG0 = b * LQ + chunk * 16;

    const int t = threadIdx.x;
    const int wave = t >> 6, lane = t & 63;

    __shared__ __align__(16) int2   s_pk[16 * 17];      // 2176 B
    __shared__ __align__(16) int2   s_w2[16 * 17];      // 2176 B (f16x2 pairs)
    __shared__ __align__(16) float  s_part[2 * 8 * 32]; // 2048 B

    // --- Phase A: offsets + pre-softmaxed weight -> corner descriptors ---
    {
        int task = t >> 4, p = t & 15, l = p >> 2;
        int row = rowG0 + task;
        float4 r4 = *(const float4*)(refp + (size_t)row * 4);
        float2 o2 = *(const float2*)(oa + (size_t)row * 384 + (h * 16 + p) * 2);
        float w = oa[(size_t)row * 384 + 256 + h * 16 + p];   // softmaxed in epilogue

        int Wl = 80 >> l;
        int vst = (l == 0) ? 0 : (l == 1) ? 6400 : (l == 2) ? 8000 : 8400;
        float x = (r4.x + o2.x * 0.125f * r4.z) * Wl - 0.5f;
        float y = (r4.y + o2.y * 0.125f * r4.w) * Wl - 0.5f;
        float x0f = floorf(x), y0f = floorf(y);
        float lx = x - x0f, ly = y - y0f;
        int x0 = (int)x0f, y0 = (int)y0f;
        int x1 = x0 + 1, y1 = y0 + 1;
        float mx0 = (x0 >= 0 && x0 < Wl) ? 1.f : 0.f;
        float mx1 = (x1 >= 0 && x1 < Wl) ? 1.f : 0.f;
        float my0 = (y0 >= 0 && y0 < Wl) ? 1.f : 0.f;
        float my1 = (y1 >= 0 && y1 < Wl) ? 1.f : 0.f;
        int cx0 = min(max(x0, 0), Wl - 1), cx1 = min(max(x1, 0), Wl - 1);
        int cy0 = min(max(y0, 0), Wl - 1), cy1 = min(max(y1, 0), Wl - 1);
        int2 r_pk;
        r_pk.x = (vst + cy0 * Wl + cx0) * 64;
        r_pk.y = ((cx1 - cx0) * 64) | (((cy1 - cy0) * Wl * 64) << 16);
        f16x2 wxy, wzw;
        wxy[0] = (_Float16)(w * (1.f - lx) * (1.f - ly) * mx0 * my0);
        wxy[1] = (_Float16)(w * lx * (1.f - ly) * mx1 * my0);
        wzw[0] = (_Float16)(w * (1.f - lx) * ly * mx0 * my1);
        wzw[1] = (_Float16)(w * lx * ly * mx1 * my1);
        int2 r_w2;
        r_w2.x = __builtin_bit_cast(int, wxy);
        r_w2.y = __builtin_bit_cast(int, wzw);
        int s = task * 17 + p;
        s_pk[s] = r_pk; s_w2[s] = r_w2;
    }
    __syncthreads();

    // --- Phase B: gather with all 16 loads hoisted, dot2 MAC ---
    {
        const int wg = wave >> 1, wp = wave & 1;
        const int pgl = lane >> 5, tk = (lane >> 2) & 7, dv2 = lane & 3;
        const int task = wg * 8 + tk;
        const int row = rowG0 + task;
        const char* vb = (const char*)v + ((size_t)(b * NH + h) * LV) * 64 + dv2 * 16;

        int2 pk[4]; f16x2 wxy[4], wzw[4];
        #pragma unroll
        for (int jj = 0; jj < 4; ++jj) {
            int p = jj * 4 + wp * 2 + pgl;       // one point per level per jj
            int s = task * 17 + p;
            pk[jj] = s_pk[s];
            int2 w2 = s_w2[s];
            wxy[jj] = __builtin_bit_cast(f16x2, w2.x);
            wzw[jj] = __builtin_bit_cast(f16x2, w2.y);
        }
        f16x8 g0[4], g1[4], g2[4], g3[4];
        #pragma unroll
        for (int jj = 0; jj < 4; ++jj) {
            int dx = pk[jj].y & 0xffff, dy = pk[jj].y >> 16;
            const char* base = vb + pk[jj].x;
            g0[jj] = *(const f16x8*)(base);
            g1[jj] = *(const f16x8*)(base + dx);
            g2[jj] = *(const f16x8*)(base + dy);
            g3[jj] = *(const f16x8*)(base + dx + dy);
        }
        float acc8[8] = {};
        #pragma unroll
        for (int jj = 0; jj < 4; ++jj)
            #pragma unroll
            for (int c = 0; c < 8; ++c) {
                f16x2 ga; ga[0] = g0[jj][c]; ga[1] = g1[jj][c];
                f16x2 gb; gb[0] = g2[jj][c]; gb[1] = g3[jj][c];
                acc8[c] = __builtin_amdgcn_fdot2(ga, wxy[jj], acc8[c], false);
                acc8[c] = __builtin_amdgcn_fdot2(gb, wzw[jj], acc8[c], false);
            }

        // combine pgl halves within wave
        #pragma unroll
        for (int c = 0; c < 8; ++c) acc8[c] += __shfl_xor(acc8[c], 32, 64);
        // cross-wave combine via LDS (dword-transposed: conflict-free)
        if (wp == 1 && lane < 32) {
            #pragma unroll
            for (int c = 0; c < 8; ++c) s_part[wg * 256 + c * 32 + lane] = acc8[c];
        }
        __syncthreads();
        if (wp == 0 && lane < 32) {
            f16x8 m8;
            #pragma unroll
            for (int c = 0; c < 8; ++c)
                m8[c] = (_Float16)(acc8[c] + s_part[wg * 256 + c * 32 + lane]);
            *(f16x8*)(mid + (size_t)row * 256 + h * 32 + dv2 * 8) = m8;
        }
    }
}

extern "C" void kernel_launch(void* const* d_in, const int* in_sizes, int n_in,
                              void* d_out, int out_size, void* d_ws, size_t ws_size,
                              hipStream_t stream) {
    const float* query  = (const float*)d_in[0];   // [4,4096,256]
    const float* refp   = (const float*)d_in[1];   // [4,4096,1,4]
    const float* value  = (const float*)d_in[2];   // [4,8500,256]
    const float* W_off  = (const float*)d_in[3];   // [256,256]
    const float* b_off  = (const float*)d_in[4];   // [256]
    const float* W_attn = (const float*)d_in[5];   // [256,128]
    const float* b_attn = (const float*)d_in[6];   // [128]
    const float* W_v    = (const float*)d_in[7];   // [256,256]
    const float* b_v    = (const float*)d_in[8];   // [256]
    const float* W_o    = (const float*)d_in[9];   // [256,256]
    const float* b_o    = (const float*)d_in[10];  // [256]

    char* ws = (char*)d_ws;
    _Float16* v_f16  = (_Float16*)(ws + 0);               // 17,408,000 B
    float*    oa_f32 = (float*)(ws + 17408000);           // 25,165,824 B
    _Float16* mid    = (_Float16*)(ws + 42573824);        //  8,388,608 B
    _Float16* WtVf   = (_Float16*)(ws + 50962432);        //    131,072 B
    _Float16* WtOAf  = (_Float16*)(ws + 51093504);        //    196,608 B
    _Float16* WtOf   = (_Float16*)(ws + 51290112);        //    131,072 B
    float*    biasOA = (float*)(ws + 51421184);           //      1,536 B

    prep_kernel<<<896, 256, 0, stream>>>(W_v, W_off, W_attn, W_o, b_off, b_attn,
                                         WtVf, WtOAf, WtOf, biasOA);
    gemm_dual_kernel<<<1044, 256, 0, stream>>>(
        value, WtVf, b_v, v_f16, query, WtOAf, biasOA, oa_f32);
    sample_kernel<<<8192, 256, 0, stream>>>(v_f16, oa_f32, refp, mid);
    gemm_o_kernel<<<1024, 256, 0, stream>>>(mid, WtOf, b_o, (float*)d_out);
}

// Round 9
// 164.862 us; speedup vs baseline: 1.1115x; 1.1115x over previous
//
#include <hip/hip_runtime.h>

#define NH 8
#define HD 32
#define SUMP 16
#define LQ 4096
#define BS 4
#define LV 8500
#define NQ (BS * LQ)   // 16384
#define MV (BS * LV)   // 34000

typedef float f32x4 __attribute__((ext_vector_type(4)));
typedef _Float16 f16x8 __attribute__((ext_vector_type(8)));
typedef _Float16 f16x2 __attribute__((ext_vector_type(2)));

// ---------- prep: weights -> fp16 fragment-linear; bias concat ----------
// frag-linear: unit block (T = n>>4, C = k>>5) of 512 fp16 at offset (T*8+C)*512;
// within: lane16 = (n&15) + 16*((k>>3)&3) at lane16*8, elem = k&7.
__global__ __launch_bounds__(256) void prep_kernel(
    const float* __restrict__ Wv, const float* __restrict__ Woff,
    const float* __restrict__ Wattn, const float* __restrict__ Wo,
    const float* __restrict__ boff, const float* __restrict__ battn,
    _Float16* __restrict__ WtVf, _Float16* __restrict__ WtOAf,
    _Float16* __restrict__ WtOf, float* __restrict__ biasOA)
{
    int g = blockIdx.x * 256 + threadIdx.x;    // 0..229375
    int gl; _Float16* dst; int which;
    if (g < 65536)       { gl = g;          dst = WtVf;  which = 0; }
    else if (g < 163840) { gl = g - 65536;  dst = WtOAf; which = 1; }
    else                 { gl = g - 163840; dst = WtOf;  which = 2; }
    int e = gl & 7, m16 = (gl >> 3) & 15, q = (gl >> 7) & 3, C = (gl >> 9) & 7, T = gl >> 12;
    int n = T * 16 + m16, k = C * 32 + q * 8 + e;
    float w;
    if (which == 0)      w = Wv[k * 256 + n];
    else if (which == 1) w = (n < 256) ? Woff[k * 256 + n] : Wattn[k * 128 + (n - 256)];
    else                 w = Wo[k * 256 + n];
    dst[gl] = (_Float16)w;
    if (blockIdx.x == 0) biasOA[threadIdx.x] = boff[threadIdx.x];
    if (blockIdx.x == 1 && threadIdx.x < 128) biasOA[256 + threadIdx.x] = battn[threadIdx.x];
}

__device__ __forceinline__ f16x8 cvt8(const float4& lo, const float4& hi) {
    f16x8 r;
    r[0] = (_Float16)lo.x; r[1] = (_Float16)lo.y; r[2] = (_Float16)lo.z; r[3] = (_Float16)lo.w;
    r[4] = (_Float16)hi.x; r[5] = (_Float16)hi.y; r[6] = (_Float16)hi.z; r[7] = (_Float16)hi.w;
    return r;
}

// ---------- single-barrier chunk GEMM (R6 config: 64-row blocks) ----------
// Block = 64 A-rows x (4*NI*16) cols, K=256. Stage ALL of A (64x256) into LDS fp16
// ONCE (16 dwordx4/thread, cvt in reg, XOR-swizzled ds_write_b128), ONE
// __syncthreads(), then 8 K-steps of ds_read_b128 + frag-linear global B (L2-hot)
// + MFMA with NO barriers -> waves free-run, no per-K-step vmcnt(0) drain.
// Swizzle: 16B-slot' = slot ^ (row&7). Read quarter (=quad) has 16 lanes over 8
// slots -> 2-way (free, m136); write quarter 16 distinct slots -> conflict-free.
template <int NI, bool V_MODE, bool A_F16>
__device__ __forceinline__ void chunk_gemm(
    const float* __restrict__ A32, const _Float16* __restrict__ A16,
    const _Float16* __restrict__ Bf, const float* __restrict__ bias,
    void* __restrict__ Cv, int M, int N, int mchunk, int ntbase,
    _Float16* __restrict__ As /* 64*256 fp16 = 32KB */)
{
    const int t = threadIdx.x;
    const int wave = t >> 6, lane = t & 63;
    const int quad = lane >> 4, l16 = lane & 15;

    // ---- stage A: 64 rows x 256 k ----
    {
        const int srow = t >> 2, schunk = t & 3;   // 4 threads/row, 64 floats each
        int gr = mchunk * 64 + srow;
        if (gr > M - 1) gr = M - 1;
        if (A_F16) {
            const _Float16* src = A16 + (size_t)gr * 256 + schunk * 64;
            f16x8 hb[8];
            #pragma unroll
            for (int j = 0; j < 8; ++j) hb[j] = *(const f16x8*)(src + j * 8);
            #pragma unroll
            for (int j = 0; j < 8; ++j) {
                int slot = (schunk * 8 + j) ^ (srow & 7);
                *(f16x8*)(As + srow * 256 + slot * 8) = hb[j];
            }
        } else {
            const float* src = A32 + (size_t)gr * 256 + schunk * 64;
            float4 buf[16];
            #pragma unroll
            for (int j = 0; j < 16; ++j) buf[j] = *(const float4*)(src + j * 4);
            #pragma unroll
            for (int j = 0; j < 8; ++j) {
                f16x8 h = cvt8(buf[2 * j], buf[2 * j + 1]);
                int slot = (schunk * 8 + j) ^ (srow & 7);
                *(f16x8*)(As + srow * 256 + slot * 8) = h;
            }
        }
    }
    __syncthreads();

    // ---- main loop: barrier-free ----
    const int ntile0 = ntbase + wave * NI;
    const _Float16* bp[NI];
    #pragma unroll
    for (int ni = 0; ni < NI; ++ni)
        bp[ni] = Bf + (size_t)(ntile0 + ni) * 4096 + lane * 8;

    f16x8 bcur[NI], bnxt[NI];
    f32x4 acc[4][NI] = {};
    #pragma unroll
    for (int ni = 0; ni < NI; ++ni) bcur[ni] = *(const f16x8*)(bp[ni]);

    #pragma unroll
    for (int k = 0; k < 8; ++k) {
        if (k < 7) {
            #pragma unroll
            for (int ni = 0; ni < NI; ++ni) bnxt[ni] = *(const f16x8*)(bp[ni] + (k + 1) * 512);
        }
        f16x8 af[4];
        #pragma unroll
        for (int mi = 0; mi < 4; ++mi) {
            int row = mi * 16 + l16;
            int slot = (quad + k * 4) ^ (row & 7);
            af[mi] = *(const f16x8*)(As + row * 256 + slot * 8);
        }
        #pragma unroll
        for (int mi = 0; mi < 4; ++mi)
            #pragma unroll
            for (int ni = 0; ni < NI; ++ni)
                acc[mi][ni] = __builtin_amdgcn_mfma_f32_16x16x32_f16(af[mi], bcur[ni], acc[mi][ni], 0, 0, 0);
        if (k < 7) {
            #pragma unroll
            for (int ni = 0; ni < NI; ++ni) bcur[ni] = bnxt[ni];
        }
    }

    // ---- epilogue: C/D col = l16, row = quad*4+r ----
    if (V_MODE) {
        #pragma unroll
        for (int mi = 0; mi < 4; ++mi) {
            int mq = mchunk * 64 + mi * 16 + quad * 4;
            size_t rb[4]; int vld[4];
            #pragma unroll
            for (int r = 0; r < 4; ++r) {
                int m = mq + r;
                vld[r] = (m < M);
                int mm = vld[r] ? m : 0;
                int b = mm / LV; int pos = mm - b * LV;
                rb[r] = ((size_t)b * NH * LV + pos) * 32;
            }
            #pragma unroll
            for (int ni = 0; ni < NI; ++ni) {
                int n = (ntile0 + ni) * 16 + l16;
                float bv = bias[n];
                int h = n >> 5, d = n & 31;
                size_t ho = (size_t)h * (LV * 32) + d;
                #pragma unroll
                for (int r = 0; r < 4; ++r)
                    if (vld[r]) ((_Float16*)Cv)[rb[r] + ho] = (_Float16)(acc[mi][ni][r] + bv);
            }
        }
    } else {
        #pragma unroll
        for (int ni = 0; ni < NI; ++ni) {
            int n = (ntile0 + ni) * 16 + l16;
            float bv = bias[n];
            #pragma unroll
            for (int mi = 0; mi < 4; ++mi) {
                int mq = mchunk * 64 + mi * 16 + quad * 4;
                #pragma unroll
                for (int r = 0; r < 4; ++r)
                    ((float*)Cv)[(size_t)(mq + r) * N + n] = acc[mi][ni][r] + bv;
            }
        }
    }
}

// V: 532 m-chunks, full N=256 per block (NI=4) -> A fetched once.
// OA: 256 m-chunks x 2 n-chunks (NI=3, 192 cols/block).
__global__ __launch_bounds__(256) void gemm_dual_kernel(
    const float* __restrict__ value, const _Float16* __restrict__ WtVf,
    const float* __restrict__ b_v, _Float16* __restrict__ v_f16,
    const float* __restrict__ query, const _Float16* __restrict__ WtOAf,
    const float* __restrict__ biasOA, float* __restrict__ oa)
{
    __shared__ __align__(16) _Float16 As[64 * 256];
    int bid = blockIdx.x;
    if (bid < 532) {
        chunk_gemm<4, true, false>(value, nullptr, WtVf, b_v, v_f16, MV, 256,
                                   bid, 0, As);
    } else {
        int g = bid - 532;                 // 0..511
        chunk_gemm<3, false, false>(query, nullptr, WtOAf, biasOA, oa, NQ, 384,
                                    g >> 1, (g & 1) * 12, As);
    }
}

// ---------- O GEMM: barrier-free, LDS-free, both operands frag-linear ----------
// mid is written by sample_kernel in frag-linear layout (same unit-block scheme
// as the weights: A-tile (T=m>>4, C=k>>5) of 512 fp16 at (T*8+C)*512, lane16 =
// (m&15)+16*((k>>3)&3), elem = k&7). Each A-fragment load is ONE dwordx4/lane
// from a contiguous 512B region (coalesced like the B side) -- unlike R1's
// failed row-major direct-A (16 lines/load + cvt chain). Wave = independent
// 32x32 C-tile (mi2 x ni2), K=256 = 8 chunks x (2 A + 2 B loads + 4 MFMA),
// 1-step prefetch, no LDS, no __syncthreads; 4096 waves = 1024 blocks.
__global__ __launch_bounds__(256) void gemm_o_kernel(
    const _Float16* __restrict__ midf, const _Float16* __restrict__ WtOf,
    const float* __restrict__ b_o, float* __restrict__ out)
{
    const int lane = threadIdx.x & 63;
    const int quad = lane >> 4, l16 = lane & 15;
    const int g = blockIdx.x * 4 + (threadIdx.x >> 6);
    const int mt = (g >> 3) * 2;          // base row-tile (32 rows)
    const int nt = (g & 7) * 2;           // base col-tile (32 cols)

    const _Float16* ap[2];
    const _Float16* bp[2];
    #pragma unroll
    for (int i = 0; i < 2; ++i) {
        ap[i] = midf + (size_t)(mt + i) * 4096 + lane * 8;
        bp[i] = WtOf + (size_t)(nt + i) * 4096 + lane * 8;
    }
    f16x8 aC[2], bC[2], aN[2], bN[2];
    f32x4 acc[2][2] = {};
    #pragma unroll
    for (int i = 0; i < 2; ++i) {
        aC[i] = *(const f16x8*)(ap[i]);
        bC[i] = *(const f16x8*)(bp[i]);
    }
    #pragma unroll
    for (int k = 0; k < 8; ++k) {
        if (k < 7) {
            #pragma unroll
            for (int i = 0; i < 2; ++i) {
                aN[i] = *(const f16x8*)(ap[i] + (k + 1) * 512);
                bN[i] = *(const f16x8*)(bp[i] + (k + 1) * 512);
            }
        }
        #pragma unroll
        for (int mi = 0; mi < 2; ++mi)
            #pragma unroll
            for (int ni = 0; ni < 2; ++ni)
                acc[mi][ni] = __builtin_amdgcn_mfma_f32_16x16x32_f16(aC[mi], bC[ni], acc[mi][ni], 0, 0, 0);
        if (k < 7) {
            #pragma unroll
            for (int i = 0; i < 2; ++i) { aC[i] = aN[i]; bC[i] = bN[i]; }
        }
    }
    #pragma unroll
    for (int ni = 0; ni < 2; ++ni) {
        int n = (nt + ni) * 16 + l16;
        float bv = b_o[n];
        #pragma unroll
        for (int mi = 0; mi < 2; ++mi) {
            int mq = (mt + mi) * 16 + quad * 4;
            #pragma unroll
            for (int r = 0; r < 4; ++r)
                out[(size_t)(mq + r) * 256 + n] = acc[mi][ni][r] + bv;
        }
    }
}

// ---------- sampling: (b,h)-specialized blocks, XCD-pinned v-slices ----------
// Block = ONE (b,h) x 16 queries. xcd = blk&7 -> each XCD serves 4 fixed (b,h)
// combos; per-XCD v working set 2.2MB < 4MB L2.
// Phase A: thread t <-> (task = t>>4, p = t&15); softmax via 16-lane shfl;
// corner weights packed to f16x2 PAIRS. Phase B: level-balanced p = jj*4 +
// wp*2 + pgl; 16 hoisted 16B gathers; dot2 MAC. Output mid is written in
// FRAG-LINEAR layout (enables LDS-free gemm_o): dest = ((row>>4)*8 + h)*512 +
// ((row&15) + 16*dv2)*8 -- still one contiguous 16B store per lane.
__global__ void sample_kernel(
    const _Float16* __restrict__ v,          // [b][h][LV][32] fp16
    const float* __restrict__ oa,            // [NQ][384]: 0..255 offsets, 256..383 logits
    const float* __restrict__ refp,          // [NQ][4]
    _Float16* __restrict__ midf)             // frag-linear [NQ/16][8][512] fp16
{
    const int blk = blockIdx.x;
    const int xcd = blk & 7, j = blk >> 3;
    const int bh = xcd * 4 + (j & 3);        // 0..31
    const int chunk = j >> 2;                // 0..255
    const int b = bh >> 3, h = bh & 7;
    const int rowG0 = b * LQ + chunk * 16;

    const int t = threadIdx.x;
    const int wave = t >> 6, lane = t & 63;

    __shared__ __align__(16) int2   s_pk[16 * 17];      // 2176 B
    __shared__ __align__(16) int2   s_w2[16 * 17];      // 2176 B (f16x2 pairs)
    __shared__ __align__(16) float  s_part[2 * 8 * 32]; // 2048 B

    // --- Phase A: logits+offsets -> softmax (shfl) -> corner descriptors ---
    {
        int task = t >> 4, p = t & 15, l = p >> 2;
        int row = rowG0 + task;
        float4 r4 = *(const float4*)(refp + (size_t)row * 4);
        float2 o2 = *(const float2*)(oa + (size_t)row * 384 + (h * 16 + p) * 2);
        float raw = oa[(size_t)row * 384 + 256 + h * 16 + p];

        // softmax over the 16 p-lanes of this task (16-lane aligned group)
        float mx = raw;
        #pragma unroll
        for (int d = 8; d >= 1; d >>= 1) mx = fmaxf(mx, __shfl_xor(mx, d, 16));
        float ex = __expf(raw - mx);
        float sm = ex;
        #pragma unroll
        for (int d = 8; d >= 1; d >>= 1) sm += __shfl_xor(sm, d, 16);
        float w = ex * __builtin_amdgcn_rcpf(sm);

        int Wl = 80 >> l;
        int vst = (l == 0) ? 0 : (l == 1) ? 6400 : (l == 2) ? 8000 : 8400;
        float x = (r4.x + o2.x * 0.125f * r4.z) * Wl - 0.5f;
        float y = (r4.y + o2.y * 0.125f * r4.w) * Wl - 0.5f;
        float x0f = floorf(x), y0f = floorf(y);
        float lx = x - x0f, ly = y - y0f;
        int x0 = (int)x0f, y0 = (int)y0f;
        int x1 = x0 + 1, y1 = y0 + 1;
        float mx0 = (x0 >= 0 && x0 < Wl) ? 1.f : 0.f;
        float mx1 = (x1 >= 0 && x1 < Wl) ? 1.f : 0.f;
        float my0 = (y0 >= 0 && y0 < Wl) ? 1.f : 0.f;
        float my1 = (y1 >= 0 && y1 < Wl) ? 1.f : 0.f;
        int cx0 = min(max(x0, 0), Wl - 1), cx1 = min(max(x1, 0), Wl - 1);
        int cy0 = min(max(y0, 0), Wl - 1), cy1 = min(max(y1, 0), Wl - 1);
        int2 r_pk;
        r_pk.x = (vst + cy0 * Wl + cx0) * 64;
        r_pk.y = ((cx1 - cx0) * 64) | (((cy1 - cy0) * Wl * 64) << 16);
        f16x2 wxy, wzw;
        wxy[0] = (_Float16)(w * (1.f - lx) * (1.f - ly) * mx0 * my0);
        wxy[1] = (_Float16)(w * lx * (1.f - ly) * mx1 * my0);
        wzw[0] = (_Float16)(w * (1.f - lx) * ly * mx0 * my1);
        wzw[1] = (_Float16)(w * lx * ly * mx1 * my1);
        int2 r_w2;
        r_w2.x = __builtin_bit_cast(int, wxy);
        r_w2.y = __builtin_bit_cast(int, wzw);
        int s = task * 17 + p;
        s_pk[s] = r_pk; s_w2[s] = r_w2;
    }
    __syncthreads();

    // --- Phase B: gather with all 16 loads hoisted, dot2 MAC ---
    {
        const int wg = wave >> 1, wp = wave & 1;
        const int pgl = lane >> 5, tk = (lane >> 2) & 7, dv2 = lane & 3;
        const int task = wg * 8 + tk;
        const int row = rowG0 + task;
        const char* vb = (const char*)v + ((size_t)(b * NH + h) * LV) * 64 + dv2 * 16;

        int2 pk[4]; f16x2 wxy[4], wzw[4];
        #pragma unroll
        for (int jj = 0; jj < 4; ++jj) {
            int p = jj * 4 + wp * 2 + pgl;       // one point per level per jj
            int s = task * 17 + p;
            pk[jj] = s_pk[s];
            int2 w2 = s_w2[s];
            wxy[jj] = __builtin_bit_cast(f16x2, w2.x);
            wzw[jj] = __builtin_bit_cast(f16x2, w2.y);
        }
        f16x8 g0[4], g1[4], g2[4], g3[4];
        #pragma unroll
        for (int jj = 0; jj < 4; ++jj) {
            int dx = pk[jj].y & 0xffff, dy = pk[jj].y >> 16;
            const char* base = vb + pk[jj].x;
            g0[jj] = *(const f16x8*)(base);
            g1[jj] = *(const f16x8*)(base + dx);
            g2[jj] = *(const f16x8*)(base + dy);
            g3[jj] = *(const f16x8*)(base + dx + dy);
        }
        float acc8[8] = {};
        #pragma unroll
        for (int jj = 0; jj < 4; ++jj)
            #pragma unroll
            for (int c = 0; c < 8; ++c) {
                f16x2 ga; ga[0] = g0[jj][c]; ga[1] = g1[jj][c];
                f16x2 gb; gb[0] = g2[jj][c]; gb[1] = g3[jj][c];
                acc8[c] = __builtin_amdgcn_fdot2(ga, wxy[jj], acc8[c], false);
                acc8[c] = __builtin_amdgcn_fdot2(gb, wzw[jj], acc8[c], false);
            }

        // combine pgl halves within wave
        #pragma unroll
        for (int c = 0; c < 8; ++c) acc8[c] += __shfl_xor(acc8[c], 32, 64);
        // cross-wave combine via LDS (dword-transposed: conflict-free)
        if (wp == 1 && lane < 32) {
            #pragma unroll
            for (int c = 0; c < 8; ++c) s_part[wg * 256 + c * 32 + lane] = acc8[c];
        }
        __syncthreads();
        if (wp == 0 && lane < 32) {
            f16x8 m8;
            #pragma unroll
            for (int c = 0; c < 8; ++c)
                m8[c] = (_Float16)(acc8[c] + s_part[wg * 256 + c * 32 + lane]);
            // frag-linear store: T=row>>4, C=h, lane16=(row&15)+16*dv2
            *(f16x8*)(midf + ((size_t)(row >> 4) * 8 + h) * 512
                           + ((row & 15) + 16 * dv2) * 8) = m8;
        }
    }
}

extern "C" void kernel_launch(void* const* d_in, const int* in_sizes, int n_in,
                              void* d_out, int out_size, void* d_ws, size_t ws_size,
                              hipStream_t stream) {
    const float* query  = (const float*)d_in[0];   // [4,4096,256]
    const float* refp   = (const float*)d_in[1];   // [4,4096,1,4]
    const float* value  = (const float*)d_in[2];   // [4,8500,256]
    const float* W_off  = (const float*)d_in[3];   // [256,256]
    const float* b_off  = (const float*)d_in[4];   // [256]
    const float* W_attn = (const float*)d_in[5];   // [256,128]
    const float* b_attn = (const float*)d_in[6];   // [128]
    const float* W_v    = (const float*)d_in[7];   // [256,256]
    const float* b_v    = (const float*)d_in[8];   // [256]
    const float* W_o    = (const float*)d_in[9];   // [256,256]
    const float* b_o    = (const float*)d_in[10];  // [256]

    char* ws = (char*)d_ws;
    _Float16* v_f16  = (_Float16*)(ws + 0);               // 17,408,000 B
    float*    oa_f32 = (float*)(ws + 17408000);           // 25,165,824 B
    _Float16* mid    = (_Float16*)(ws + 42573824);        //  8,388,608 B (frag-linear)
    _Float16* WtVf   = (_Float16*)(ws + 50962432);        //    131,072 B
    _Float16* WtOAf  = (_Float16*)(ws + 51093504);        //    196,608 B
    _Float16* WtOf   = (_Float16*)(ws + 51290112);        //    131,072 B
    float*    biasOA = (float*)(ws + 51421184);           //      1,536 B

    prep_kernel<<<896, 256, 0, stream>>>(W_v, W_off, W_attn, W_o, b_off, b_attn,
                                         WtVf, WtOAf, WtOf, biasOA);
    gemm_dual_kernel<<<1044, 256, 0, stream>>>(
        value, WtVf, b_v, v_f16, query, WtOAf, biasOA, oa_f32);
    sample_kernel<<<8192, 256, 0, stream>>>(v_f16, oa_f32, refp, mid);
    gemm_o_kernel<<<1024, 256, 0, stream>>>(mid, WtOf, b_o, (float*)d_out);
}

// Round 10
// 164.101 us; speedup vs baseline: 1.1166x; 1.0046x over previous
//
#include <hip/hip_runtime.h>

#define NH 8
#define HD 32
#define SUMP 16
#define LQ 4096
#define BS 4
#define LV 8500
#define NQ (BS * LQ)   // 16384
#define MV (BS * LV)   // 34000

typedef float f32x4 __attribute__((ext_vector_type(4)));
typedef _Float16 f16x8 __attribute__((ext_vector_type(8)));
typedef _Float16 f16x4 __attribute__((ext_vector_type(4)));
typedef _Float16 f16x2 __attribute__((ext_vector_type(2)));

// ---------- prep: weights -> fp16 fragment-linear; bias concat ----------
// frag-linear: unit block (T = n>>4, C = k>>5) of 512 fp16 at offset (T*8+C)*512;
// within: lane16 = (n&15) + 16*((k>>3)&3) at lane16*8, elem = k&7.
__global__ __launch_bounds__(256) void prep_kernel(
    const float* __restrict__ Wv, const float* __restrict__ Woff,
    const float* __restrict__ Wattn, const float* __restrict__ Wo,
    const float* __restrict__ boff, const float* __restrict__ battn,
    _Float16* __restrict__ WtVf, _Float16* __restrict__ WtOAf,
    _Float16* __restrict__ WtOf, float* __restrict__ biasOA)
{
    int g = blockIdx.x * 256 + threadIdx.x;    // 0..229375
    int gl; _Float16* dst; int which;
    if (g < 65536)       { gl = g;          dst = WtVf;  which = 0; }
    else if (g < 163840) { gl = g - 65536;  dst = WtOAf; which = 1; }
    else                 { gl = g - 163840; dst = WtOf;  which = 2; }
    int e = gl & 7, m16 = (gl >> 3) & 15, q = (gl >> 7) & 3, C = (gl >> 9) & 7, T = gl >> 12;
    int n = T * 16 + m16, k = C * 32 + q * 8 + e;
    float w;
    if (which == 0)      w = Wv[k * 256 + n];
    else if (which == 1) w = (n < 256) ? Woff[k * 256 + n] : Wattn[k * 128 + (n - 256)];
    else                 w = Wo[k * 256 + n];
    dst[gl] = (_Float16)w;
    if (blockIdx.x == 0) biasOA[threadIdx.x] = boff[threadIdx.x];
    if (blockIdx.x == 1 && threadIdx.x < 128) biasOA[256 + threadIdx.x] = battn[threadIdx.x];
}

__device__ __forceinline__ f16x8 cvt8(const float4& lo, const float4& hi) {
    f16x8 r;
    r[0] = (_Float16)lo.x; r[1] = (_Float16)lo.y; r[2] = (_Float16)lo.z; r[3] = (_Float16)lo.w;
    r[4] = (_Float16)hi.x; r[5] = (_Float16)hi.y; r[6] = (_Float16)hi.z; r[7] = (_Float16)hi.w;
    return r;
}

// ---------- single-barrier chunk GEMM, SWAPPED MFMA operands ----------
// Block = 64 A-rows x (4*NI*16) cols, K=256. Stage ALL of A (64x256) into LDS fp16
// ONCE (16 dwordx4/thread, cvt in reg, XOR-swizzled ds_write_b128), ONE
// __syncthreads(), then 8 K-steps of ds_read_b128 + frag-linear global B (L2-hot)
// + MFMA, no further barriers. Swizzle slot' = slot ^ (row&7).
// OPERAND SWAP: acc = mfma(b_weight, a_value, acc) -> C is TRANSPOSED: lane
// holds 4 CONSECUTIVE OUTPUT FEATURES (row = n-dim = quad*4+r) for ONE m
// (col = l16). Epilogue then packs 4 features into ONE 8B fp16x4 store (V:
// was 64 guarded 2B stores/lane) or ONE float4 store (OA: was 48 4B stores).
// A/B fragments share the same lane->(idx,k) map for 16x16x32, so the swap is
// exact; K-loop untouched.
template <int NI, bool V_MODE>
__device__ __forceinline__ void chunk_gemm(
    const float* __restrict__ A32,
    const _Float16* __restrict__ Bf, const float* __restrict__ bias,
    void* __restrict__ Cv, int M, int N, int mchunk, int ntbase,
    _Float16* __restrict__ As /* 64*256 fp16 = 32KB */)
{
    const int t = threadIdx.x;
    const int wave = t >> 6, lane = t & 63;
    const int quad = lane >> 4, l16 = lane & 15;

    // ---- stage A: 64 rows x 256 k ----
    {
        const int srow = t >> 2, schunk = t & 3;   // 4 threads/row, 64 floats each
        int gr = mchunk * 64 + srow;
        if (gr > M - 1) gr = M - 1;
        const float* src = A32 + (size_t)gr * 256 + schunk * 64;
        float4 buf[16];
        #pragma unroll
        for (int j = 0; j < 16; ++j) buf[j] = *(const float4*)(src + j * 4);
        #pragma unroll
        for (int j = 0; j < 8; ++j) {
            f16x8 h = cvt8(buf[2 * j], buf[2 * j + 1]);
            int slot = (schunk * 8 + j) ^ (srow & 7);
            *(f16x8*)(As + srow * 256 + slot * 8) = h;
        }
    }
    __syncthreads();

    // ---- main loop: barrier-free ----
    const int ntile0 = ntbase + wave * NI;
    const _Float16* bp[NI];
    #pragma unroll
    for (int ni = 0; ni < NI; ++ni)
        bp[ni] = Bf + (size_t)(ntile0 + ni) * 4096 + lane * 8;

    f16x8 bcur[NI], bnxt[NI];
    f32x4 acc[4][NI] = {};
    #pragma unroll
    for (int ni = 0; ni < NI; ++ni) bcur[ni] = *(const f16x8*)(bp[ni]);

    #pragma unroll
    for (int k = 0; k < 8; ++k) {
        if (k < 7) {
            #pragma unroll
            for (int ni = 0; ni < NI; ++ni) bnxt[ni] = *(const f16x8*)(bp[ni] + (k + 1) * 512);
        }
        f16x8 af[4];
        #pragma unroll
        for (int mi = 0; mi < 4; ++mi) {
            int row = mi * 16 + l16;
            int slot = (quad + k * 4) ^ (row & 7);
            af[mi] = *(const f16x8*)(As + row * 256 + slot * 8);
        }
        #pragma unroll
        for (int mi = 0; mi < 4; ++mi)
            #pragma unroll
            for (int ni = 0; ni < NI; ++ni)
                acc[mi][ni] = __builtin_amdgcn_mfma_f32_16x16x32_f16(bcur[ni], af[mi], acc[mi][ni], 0, 0, 0);
        if (k < 7) {
            #pragma unroll
            for (int ni = 0; ni < NI; ++ni) bcur[ni] = bnxt[ni];
        }
    }

    // ---- epilogue (transposed C): row = n-feature = quad*4+r, col = m = l16 ----
    if (V_MODE) {
        #pragma unroll
        for (int mi = 0; mi < 4; ++mi) {
            int m = mchunk * 64 + mi * 16 + l16;
            int vld = (m < M);
            int mm = vld ? m : 0;
            int bb = mm / LV; int pos = mm - bb * LV;
            size_t pbase = ((size_t)bb * NH * LV + pos) * 32;
            #pragma unroll
            for (int ni = 0; ni < NI; ++ni) {
                int n0 = (ntile0 + ni) * 16 + quad * 4;
                float4 bv4 = *(const float4*)(bias + n0);
                int h = n0 >> 5, d0 = n0 & 31;
                f16x4 o;
                o[0] = (_Float16)(acc[mi][ni][0] + bv4.x);
                o[1] = (_Float16)(acc[mi][ni][1] + bv4.y);
                o[2] = (_Float16)(acc[mi][ni][2] + bv4.z);
                o[3] = (_Float16)(acc[mi][ni][3] + bv4.w);
                if (vld)
                    *(f16x4*)((_Float16*)Cv + pbase + (size_t)h * (LV * 32) + d0) = o;
            }
        }
    } else {
        #pragma unroll
        for (int ni = 0; ni < NI; ++ni) {
            int n0 = (ntile0 + ni) * 16 + quad * 4;
            float4 bv4 = *(const float4*)(bias + n0);
            #pragma unroll
            for (int mi = 0; mi < 4; ++mi) {
                int m = mchunk * 64 + mi * 16 + l16;
                float4 o;
                o.x = acc[mi][ni][0] + bv4.x;
                o.y = acc[mi][ni][1] + bv4.y;
                o.z = acc[mi][ni][2] + bv4.z;
                o.w = acc[mi][ni][3] + bv4.w;
                *(float4*)((float*)Cv + (size_t)m * N + n0) = o;
            }
        }
    }
}

// V: 532 m-chunks, full N=256 per block (NI=4) -> A fetched once.
// OA: 256 m-chunks x 2 n-chunks (NI=3, 192 cols/block).
__global__ __launch_bounds__(256) void gemm_dual_kernel(
    const float* __restrict__ value, const _Float16* __restrict__ WtVf,
    const float* __restrict__ b_v, _Float16* __restrict__ v_f16,
    const float* __restrict__ query, const _Float16* __restrict__ WtOAf,
    const float* __restrict__ biasOA, float* __restrict__ oa)
{
    __shared__ __align__(16) _Float16 As[64 * 256];
    int bid = blockIdx.x;
    if (bid < 532) {
        chunk_gemm<4, true>(value, WtVf, b_v, v_f16, MV, 256, bid, 0, As);
    } else {
        int g = bid - 532;                 // 0..511
        chunk_gemm<3, false>(query, WtOAf, biasOA, oa, NQ, 384,
                             g >> 1, (g & 1) * 12, As);
    }
}

// ---------- O GEMM: barrier-free, LDS-free, both operands frag-linear ----------
// mid written frag-linear by sample (same unit-block scheme as weights). Each
// fragment load = ONE dwordx4/lane from a contiguous 512B region. Wave =
// independent 32x32 C-tile, K=256 = 8 chunks, 1-step prefetch, no LDS/barrier.
// SWAPPED operands: lane holds 4 consecutive n for one m -> float4 stores
// (was 16x4B, now 4x16B).
__global__ __launch_bounds__(256) void gemm_o_kernel(
    const _Float16* __restrict__ midf, const _Float16* __restrict__ WtOf,
    const float* __restrict__ b_o, float* __restrict__ out)
{
    const int lane = threadIdx.x & 63;
    const int quad = lane >> 4, l16 = lane & 15;
    const int g = blockIdx.x * 4 + (threadIdx.x >> 6);
    const int mt = (g >> 3) * 2;          // base row-tile (32 rows)
    const int nt = (g & 7) * 2;           // base col-tile (32 cols)

    const _Float16* ap[2];
    const _Float16* bp[2];
    #pragma unroll
    for (int i = 0; i < 2; ++i) {
        ap[i] = midf + (size_t)(mt + i) * 4096 + lane * 8;
        bp[i] = WtOf + (size_t)(nt + i) * 4096 + lane * 8;
    }
    f16x8 aC[2], bC[2], aN[2], bN[2];
    f32x4 acc[2][2] = {};
    #pragma unroll
    for (int i = 0; i < 2; ++i) {
        aC[i] = *(const f16x8*)(ap[i]);
        bC[i] = *(const f16x8*)(bp[i]);
    }
    #pragma unroll
    for (int k = 0; k < 8; ++k) {
        if (k < 7) {
            #pragma unroll
            for (int i = 0; i < 2; ++i) {
                aN[i] = *(const f16x8*)(ap[i] + (k + 1) * 512);
                bN[i] = *(const f16x8*)(bp[i] + (k + 1) * 512);
            }
        }
        #pragma unroll
        for (int mi = 0; mi < 2; ++mi)
            #pragma unroll
            for (int ni = 0; ni < 2; ++ni)
                acc[mi][ni] = __builtin_amdgcn_mfma_f32_16x16x32_f16(bC[ni], aC[mi], acc[mi][ni], 0, 0, 0);
        if (k < 7) {
            #pragma unroll
            for (int i = 0; i < 2; ++i) { aC[i] = aN[i]; bC[i] = bN[i]; }
        }
    }
    #pragma unroll
    for (int mi = 0; mi < 2; ++mi) {
        int m = (mt + mi) * 16 + l16;
        #pragma unroll
        for (int ni = 0; ni < 2; ++ni) {
            int n0 = (nt + ni) * 16 + quad * 4;
            float4 bv4 = *(const float4*)(b_o + n0);
            float4 o;
            o.x = acc[mi][ni][0] + bv4.x;
            o.y = acc[mi][ni][1] + bv4.y;
            o.z = acc[mi][ni][2] + bv4.z;
            o.w = acc[mi][ni][3] + bv4.w;
            *(float4*)(out + (size_t)m * 256 + n0) = o;
        }
    }
}

// ---------- sampling: (b,h)-specialized blocks, XCD-pinned v-slices ----------
// Block = ONE (b,h) x 16 queries. xcd = blk&7 -> each XCD serves 4 fixed (b,h)
// combos; per-XCD v working set 2.2MB < 4MB L2.
// Phase A: thread t <-> (task = t>>4, p = t&15); softmax via 16-lane shfl;
// corner weights packed to f16x2 PAIRS. Phase B: level-balanced p = jj*4 +
// wp*2 + pgl; 16 hoisted 16B gathers; dot2 MAC. mid written FRAG-LINEAR
// (enables LDS-free gemm_o): one contiguous 16B store per lane.
__global__ void sample_kernel(
    const _Float16* __restrict__ v,          // [b][h][LV][32] fp16
    const float* __restrict__ oa,            // [NQ][384]: 0..255 offsets, 256..383 logits
    const float* __restrict__ refp,          // [NQ][4]
    _Float16* __restrict__ midf)             // frag-linear [NQ/16][8][512] fp16
{
    const int blk = blockIdx.x;
    const int xcd = blk & 7, j = blk >> 3;
    const int bh = xcd * 4 + (j & 3);        // 0..31
    const int chunk = j >> 2;                // 0..255
    const int b = bh >> 3, h = bh & 7;
    const int rowG0 = b * LQ + chunk * 16;

    const int t = threadIdx.x;
    const int wave = t >> 6, lane = t & 63;

    __shared__ __align__(16) int2   s_pk[16 * 17];      // 2176 B
    __shared__ __align__(16) int2   s_w2[16 * 17];      // 2176 B (f16x2 pairs)
    __shared__ __align__(16) float  s_part[2 * 8 * 32]; // 2048 B

    // --- Phase A: logits+offsets -> softmax (shfl) -> corner descriptors ---
    {
        int task = t >> 4, p = t & 15, l = p >> 2;
        int row = rowG0 + task;
        float4 r4 = *(const float4*)(refp + (size_t)row * 4);
        float2 o2 = *(const float2*)(oa + (size_t)row * 384 + (h * 16 + p) * 2);
        float raw = oa[(size_t)row * 384 + 256 + h * 16 + p];

        // softmax over the 16 p-lanes of this task (16-lane aligned group)
        float mx = raw;
        #pragma unroll
        for (int d = 8; d >= 1; d >>= 1) mx = fmaxf(mx, __shfl_xor(mx, d, 16));
        float ex = __expf(raw - mx);
        float sm = ex;
        #pragma unroll
        for (int d = 8; d >= 1; d >>= 1) sm += __shfl_xor(sm, d, 16);
        float w = ex * __builtin_amdgcn_rcpf(sm);

        int Wl = 80 >> l;
        int vst = (l == 0) ? 0 : (l == 1) ? 6400 : (l == 2) ? 8000 : 8400;
        float x = (r4.x + o2.x * 0.125f * r4.z) * Wl - 0.5f;
        float y = (r4.y + o2.y * 0.125f * r4.w) * Wl - 0.5f;
        float x0f = floorf(x), y0f = floorf(y);
        float lx = x - x0f, ly = y - y0f;
        int x0 = (int)x0f, y0 = (int)y0f;
        int x1 = x0 + 1, y1 = y0 + 1;
        float mx0 = (x0 >= 0 && x0 < Wl) ? 1.f : 0.f;
        float mx1 = (x1 >= 0 && x1 < Wl) ? 1.f : 0.f;
        float my0 = (y0 >= 0 && y0 < Wl) ? 1.f : 0.f;
        float my1 = (y1 >= 0 && y1 < Wl) ? 1.f : 0.f;
        int cx0 = min(max(x0, 0), Wl - 1), cx1 = min(max(x1, 0), Wl - 1);
        int cy0 = min(max(y0, 0), Wl - 1), cy1 = min(max(y1, 0), Wl - 1);
        int2 r_pk;
        r_pk.x = (vst + cy0 * Wl + cx0) * 64;
        r_pk.y = ((cx1 - cx0) * 64) | (((cy1 - cy0) * Wl * 64) << 16);
        f16x2 wxy, wzw;
        wxy[0] = (_Float16)(w * (1.f - lx) * (1.f - ly) * mx0 * my0);
        wxy[1] = (_Float16)(w * lx * (1.f - ly) * mx1 * my0);
        wzw[0] = (_Float16)(w * (1.f - lx) * ly * mx0 * my1);
        wzw[1] = (_Float16)(w * lx * ly * mx1 * my1);
        int2 r_w2;
        r_w2.x = __builtin_bit_cast(int, wxy);
        r_w2.y = __builtin_bit_cast(int, wzw);
        int s = task * 17 + p;
        s_pk[s] = r_pk; s_w2[s] = r_w2;
    }
    __syncthreads();

    // --- Phase B: gather with all 16 loads hoisted, dot2 MAC ---
    {
        const int wg = wave >> 1, wp = wave & 1;
        const int pgl = lane >> 5, tk = (lane >> 2) & 7, dv2 = lane & 3;
        const int task = wg * 8 + tk;
        const int row = rowG0 + task;
        const char* vb = (const char*)v + ((size_t)(b * NH + h) * LV) * 64 + dv2 * 16;

        int2 pk[4]; f16x2 wxy[4], wzw[4];
        #pragma unroll
        for (int jj = 0; jj < 4; ++jj) {
            int p = jj * 4 + wp * 2 + pgl;       // one point per level per jj
            int s = task * 17 + p;
            pk[jj] = s_pk[s];
            int2 w2 = s_w2[s];
            wxy[jj] = __builtin_bit_cast(f16x2, w2.x);
            wzw[jj] = __builtin_bit_cast(f16x2, w2.y);
        }
        f16x8 g0[4], g1[4], g2[4], g3[4];
        #pragma unroll
        for (int jj = 0; jj < 4; ++jj) {
            int dx = pk[jj].y & 0xffff, dy = pk[jj].y >> 16;
            const char* base = vb + pk[jj].x;
            g0[jj] = *(const f16x8*)(base);
            g1[jj] = *(const f16x8*)(base + dx);
            g2[jj] = *(const f16x8*)(base + dy);
            g3[jj] = *(const f16x8*)(base + dx + dy);
        }
        float acc8[8] = {};
        #pragma unroll
        for (int jj = 0; jj < 4; ++jj)
            #pragma unroll
            for (int c = 0; c < 8; ++c) {
                f16x2 ga; ga[0] = g0[jj][c]; ga[1] = g1[jj][c];
                f16x2 gb; gb[0] = g2[jj][c]; gb[1] = g3[jj][c];
                acc8[c] = __builtin_amdgcn_fdot2(ga, wxy[jj], acc8[c], false);
                acc8[c] = __builtin_amdgcn_fdot2(gb, wzw[jj], acc8[c], false);
            }

        // combine pgl halves within wave
        #pragma unroll
        for (int c = 0; c < 8; ++c) acc8[c] += __shfl_xor(acc8[c], 32, 64);
        // cross-wave combine via LDS (dword-transposed: conflict-free)
        if (wp == 1 && lane < 32) {
            #pragma unroll
            for (int c = 0; c < 8; ++c) s_part[wg * 256 + c * 32 + lane] = acc8[c];
        }
        __syncthreads();
        if (wp == 0 && lane < 32) {
            f16x8 m8;
            #pragma unroll
            for (int c = 0; c < 8; ++c)
                m8[c] = (_Float16)(acc8[c] + s_part[wg * 256 + c * 32 + lane]);
            // frag-linear store: T=row>>4, C=h, lane16=(row&15)+16*dv2
            *(f16x8*)(midf + ((size_t)(row >> 4) * 8 + h) * 512
                           + ((row & 15) + 16 * dv2) * 8) = m8;
        }
    }
}

extern "C" void kernel_launch(void* const* d_in, const int* in_sizes, int n_in,
                              void* d_out, int out_size, void* d_ws, size_t ws_size,
                              hipStream_t stream) {
    const float* query  = (const float*)d_in[0];   // [4,4096,256]
    const float* refp   = (const float*)d_in[1];   // [4,4096,1,4]
    const float* value  = (const float*)d_in[2];   // [4,8500,256]
    const float* W_off  = (const float*)d_in[3];   // [256,256]
    const float* b_off  = (const float*)d_in[4];   // [256]
    const float* W_attn = (const float*)d_in[5];   // [256,128]
    const float* b_attn = (const float*)d_in[6];   // [128]
    const float* W_v    = (const float*)d_in[7];   // [256,256]
    const float* b_v    = (const float*)d_in[8];   // [256]
    const float* W_o    = (const float*)d_in[9];   // [256,256]
    const float* b_o    = (const float*)d_in[10];  // [256]

    char* ws = (char*)d_ws;
    _Float16* v_f16  = (_Float16*)(ws + 0);               // 17,408,000 B
    float*    oa_f32 = (float*)(ws + 17408000);           // 25,165,824 B
    _Float16* mid    = (_Float16*)(ws + 42573824);        //  8,388,608 B (frag-linear)
    _Float16* WtVf   = (_Float16*)(ws + 50962432);        //    131,072 B
    _Float16* WtOAf  = (_Float16*)(ws + 51093504);        //    196,608 B
    _Float16* WtOf   = (_Float16*)(ws + 51290112);        //    131,072 B
    float*    biasOA = (float*)(ws + 51421184);           //      1,536 B

    prep_kernel<<<896, 256, 0, stream>>>(W_v, W_off, W_attn, W_o, b_off, b_attn,
                                         WtVf, WtOAf, WtOf, biasOA);
    gemm_dual_kernel<<<1044, 256, 0, stream>>>(
        value, WtVf, b_v, v_f16, query, WtOAf, biasOA, oa_f32);
    sample_kernel<<<8192, 256, 0, stream>>>(v_f16, oa_f32, refp, mid);
    gemm_o_kernel<<<1024, 256, 0, stream>>>(mid, WtOf, b_o, (float*)d_out);
}

// Round 12
// 163.782 us; speedup vs baseline: 1.1188x; 1.0019x over previous
//
#include <hip/hip_runtime.h>

#define NH 8
#define HD 32
#define SUMP 16
#define LQ 4096
#define BS 4
#define LV 8500
#define NQ (BS * LQ)   // 16384
#define MV (BS * LV)   // 34000

typedef float f32x4 __attribute__((ext_vector_type(4)));
typedef _Float16 f16x8 __attribute__((ext_vector_type(8)));
typedef _Float16 f16x4 __attribute__((ext_vector_type(4)));
typedef _Float16 f16x2 __attribute__((ext_vector_type(2)));

// ---------- prep: weights -> fp16 fragment-linear; bias concat ----------
// frag-linear: unit block (T = n>>4, C = k>>5) of 512 fp16 at offset (T*8+C)*512;
// within: lane16 = (n&15) + 16*((k>>3)&3) at lane16*8, elem = k&7.
__global__ __launch_bounds__(256) void prep_kernel(
    const float* __restrict__ Wv, const float* __restrict__ Woff,
    const float* __restrict__ Wattn, const float* __restrict__ Wo,
    const float* __restrict__ boff, const float* __restrict__ battn,
    _Float16* __restrict__ WtVf, _Float16* __restrict__ WtOAf,
    _Float16* __restrict__ WtOf, float* __restrict__ biasOA)
{
    int g = blockIdx.x * 256 + threadIdx.x;    // 0..229375
    int gl; _Float16* dst; int which;
    if (g < 65536)       { gl = g;          dst = WtVf;  which = 0; }
    else if (g < 163840) { gl = g - 65536;  dst = WtOAf; which = 1; }
    else                 { gl = g - 163840; dst = WtOf;  which = 2; }
    int e = gl & 7, m16 = (gl >> 3) & 15, q = (gl >> 7) & 3, C = (gl >> 9) & 7, T = gl >> 12;
    int n = T * 16 + m16, k = C * 32 + q * 8 + e;
    float w;
    if (which == 0)      w = Wv[k * 256 + n];
    else if (which == 1) w = (n < 256) ? Woff[k * 256 + n] : Wattn[k * 128 + (n - 256)];
    else                 w = Wo[k * 256 + n];
    dst[gl] = (_Float16)w;
    if (blockIdx.x == 0) biasOA[threadIdx.x] = boff[threadIdx.x];
    if (blockIdx.x == 1 && threadIdx.x < 128) biasOA[256 + threadIdx.x] = battn[threadIdx.x];
}

__device__ __forceinline__ f16x8 cvt8(const float4& lo, const float4& hi) {
    f16x8 r;
    r[0] = (_Float16)lo.x; r[1] = (_Float16)lo.y; r[2] = (_Float16)lo.z; r[3] = (_Float16)lo.w;
    r[4] = (_Float16)hi.x; r[5] = (_Float16)hi.y; r[6] = (_Float16)hi.z; r[7] = (_Float16)hi.w;
    return r;
}

// ---------- single-barrier chunk GEMM, swapped MFMA operands (R10 config) ----------
// Block = 64 A-rows x (4*NI*16) cols, K=256. Stage A (64x256) to LDS fp16 once,
// ONE __syncthreads(), 8 K-steps of ds_read_b128 + frag-linear global B + MFMA,
// no further barriers. Swizzle slot' = slot ^ (row&7).
// OPERAND SWAP: acc = mfma(b_weight, a_value, acc) -> lane holds 4 consecutive
// output features for one m -> packed f16x4 / float4 stores.
template <int NI, bool V_MODE>
__device__ __forceinline__ void chunk_gemm(
    const float* __restrict__ A32,
    const _Float16* __restrict__ Bf, const float* __restrict__ bias,
    void* __restrict__ Cv, int M, int N, int mchunk, int ntbase,
    _Float16* __restrict__ As /* 64*256 fp16 = 32KB */)
{
    const int t = threadIdx.x;
    const int wave = t >> 6, lane = t & 63;
    const int quad = lane >> 4, l16 = lane & 15;

    // ---- stage A: 64 rows x 256 k ----
    {
        const int srow = t >> 2, schunk = t & 3;   // 4 threads/row, 64 floats each
        int gr = mchunk * 64 + srow;
        if (gr > M - 1) gr = M - 1;
        const float* src = A32 + (size_t)gr * 256 + schunk * 64;
        float4 buf[16];
        #pragma unroll
        for (int j = 0; j < 16; ++j) buf[j] = *(const float4*)(src + j * 4);
        #pragma unroll
        for (int j = 0; j < 8; ++j) {
            f16x8 h = cvt8(buf[2 * j], buf[2 * j + 1]);
            int slot = (schunk * 8 + j) ^ (srow & 7);
            *(f16x8*)(As + srow * 256 + slot * 8) = h;
        }
    }
    __syncthreads();

    // ---- main loop: barrier-free ----
    const int ntile0 = ntbase + wave * NI;
    const _Float16* bp[NI];
    #pragma unroll
    for (int ni = 0; ni < NI; ++ni)
        bp[ni] = Bf + (size_t)(ntile0 + ni) * 4096 + lane * 8;

    f16x8 bcur[NI], bnxt[NI];
    f32x4 acc[4][NI] = {};
    #pragma unroll
    for (int ni = 0; ni < NI; ++ni) bcur[ni] = *(const f16x8*)(bp[ni]);

    #pragma unroll
    for (int k = 0; k < 8; ++k) {
        if (k < 7) {
            #pragma unroll
            for (int ni = 0; ni < NI; ++ni) bnxt[ni] = *(const f16x8*)(bp[ni] + (k + 1) * 512);
        }
        f16x8 af[4];
        #pragma unroll
        for (int mi = 0; mi < 4; ++mi) {
            int row = mi * 16 + l16;
            int slot = (quad + k * 4) ^ (row & 7);
            af[mi] = *(const f16x8*)(As + row * 256 + slot * 8);
        }
        #pragma unroll
        for (int mi = 0; mi < 4; ++mi)
            #pragma unroll
            for (int ni = 0; ni < NI; ++ni)
                acc[mi][ni] = __builtin_amdgcn_mfma_f32_16x16x32_f16(bcur[ni], af[mi], acc[mi][ni], 0, 0, 0);
        if (k < 7) {
            #pragma unroll
            for (int ni = 0; ni < NI; ++ni) bcur[ni] = bnxt[ni];
        }
    }

    // ---- epilogue (transposed C): row = n-feature = quad*4+r, col = m = l16 ----
    if (V_MODE) {
        #pragma unroll
        for (int mi = 0; mi < 4; ++mi) {
            int m = mchunk * 64 + mi * 16 + l16;
            int vld = (m < M);
            int mm = vld ? m : 0;
            int bb = mm / LV; int pos = mm - bb * LV;
            size_t pbase = ((size_t)bb * NH * LV + pos) * 32;
            #pragma unroll
            for (int ni = 0; ni < NI; ++ni) {
                int n0 = (ntile0 + ni) * 16 + quad * 4;
                float4 bv4 = *(const float4*)(bias + n0);
                int h = n0 >> 5, d0 = n0 & 31;
                f16x4 o;
                o[0] = (_Float16)(acc[mi][ni][0] + bv4.x);
                o[1] = (_Float16)(acc[mi][ni][1] + bv4.y);
                o[2] = (_Float16)(acc[mi][ni][2] + bv4.z);
                o[3] = (_Float16)(acc[mi][ni][3] + bv4.w);
                if (vld)
                    *(f16x4*)((_Float16*)Cv + pbase + (size_t)h * (LV * 32) + d0) = o;
            }
        }
    } else {
        #pragma unroll
        for (int ni = 0; ni < NI; ++ni) {
            int n0 = (ntile0 + ni) * 16 + quad * 4;
            float4 bv4 = *(const float4*)(bias + n0);
            #pragma unroll
            for (int mi = 0; mi < 4; ++mi) {
                int m = mchunk * 64 + mi * 16 + l16;
                float4 o;
                o.x = acc[mi][ni][0] + bv4.x;
                o.y = acc[mi][ni][1] + bv4.y;
                o.z = acc[mi][ni][2] + bv4.z;
                o.w = acc[mi][ni][3] + bv4.w;
                *(float4*)((float*)Cv + (size_t)m * N + n0) = o;
            }
        }
    }
}

// V: 532 m-chunks, full N=256 per block (NI=4). OA: 256 m-chunks x 2 n-chunks
// (NI=3, 192 cols). INTERLEAVED block mapping (pure permutation of blockIdx ->
// work; per-block work byte-identical to R10): even bid<1024 -> V bid/2, odd ->
// OA bid/2, bid>=1024 -> V 512+. Mixes value-heavy and query-heavy traffic
// across CUs/XCDs from dispatch start and shortens the same-type tail.
__global__ __launch_bounds__(256) void gemm_dual_kernel(
    const float* __restrict__ value, const _Float16* __restrict__ WtVf,
    const float* __restrict__ b_v, _Float16* __restrict__ v_f16,
    const float* __restrict__ query, const _Float16* __restrict__ WtOAf,
    const float* __restrict__ biasOA, float* __restrict__ oa)
{
    __shared__ __align__(16) _Float16 As[64 * 256];
    int bid = blockIdx.x;
    if (bid < 1024) {
        if ((bid & 1) == 0) {
            chunk_gemm<4, true>(value, WtVf, b_v, v_f16, MV, 256, bid >> 1, 0, As);
        } else {
            int g = bid >> 1;              // 0..511
            chunk_gemm<3, false>(query, WtOAf, biasOA, oa, NQ, 384,
                                 g >> 1, (g & 1) * 12, As);
        }
    } else {
        chunk_gemm<4, true>(value, WtVf, b_v, v_f16, MV, 256, 512 + (bid - 1024), 0, As);
    }
}

// ---------- O GEMM: barrier-free, LDS-free, both operands frag-linear ----------
// mid written frag-linear by sample. Each fragment load = ONE dwordx4/lane from
// a contiguous 512B region. Wave = independent 32x32 C-tile, K=256 = 8 chunks,
// 1-step prefetch, no LDS/barrier. Swapped operands -> float4 stores.
__global__ __launch_bounds__(256) void gemm_o_kernel(
    const _Float16* __restrict__ midf, const _Float16* __restrict__ WtOf,
    const float* __restrict__ b_o, float* __restrict__ out)
{
    const int lane = threadIdx.x & 63;
    const int quad = lane >> 4, l16 = lane & 15;
    const int g = blockIdx.x * 4 + (threadIdx.x >> 6);
    const int mt = (g >> 3) * 2;          // base row-tile (32 rows)
    const int nt = (g & 7) * 2;           // base col-tile (32 cols)

    const _Float16* ap[2];
    const _Float16* bp[2];
    #pragma unroll
    for (int i = 0; i < 2; ++i) {
        ap[i] = midf + (size_t)(mt + i) * 4096 + lane * 8;
        bp[i] = WtOf + (size_t)(nt + i) * 4096 + lane * 8;
    }
    f16x8 aC[2], bC[2], aN[2], bN[2];
    f32x4 acc[2][2] = {};
    #pragma unroll
    for (int i = 0; i < 2; ++i) {
        aC[i] = *(const f16x8*)(ap[i]);
        bC[i] = *(const f16x8*)(bp[i]);
    }
    #pragma unroll
    for (int k = 0; k < 8; ++k) {
        if (k < 7) {
            #pragma unroll
            for (int i = 0; i < 2; ++i) {
                aN[i] = *(const f16x8*)(ap[i] + (k + 1) * 512);
                bN[i] = *(const f16x8*)(bp[i] + (k + 1) * 512);
            }
        }
        #pragma unroll
        for (int mi = 0; mi < 2; ++mi)
            #pragma unroll
            for (int ni = 0; ni < 2; ++ni)
                acc[mi][ni] = __builtin_amdgcn_mfma_f32_16x16x32_f16(bC[ni], aC[mi], acc[mi][ni], 0, 0, 0);
        if (k < 7) {
            #pragma unroll
            for (int i = 0; i < 2; ++i) { aC[i] = aN[i]; bC[i] = bN[i]; }
        }
    }
    #pragma unroll
    for (int mi = 0; mi < 2; ++mi) {
        int m = (mt + mi) * 16 + l16;
        #pragma unroll
        for (int ni = 0; ni < 2; ++ni) {
            int n0 = (nt + ni) * 16 + quad * 4;
            float4 bv4 = *(const float4*)(b_o + n0);
            float4 o;
            o.x = acc[mi][ni][0] + bv4.x;
            o.y = acc[mi][ni][1] + bv4.y;
            o.z = acc[mi][ni][2] + bv4.z;
            o.w = acc[mi][ni][3] + bv4.w;
            *(float4*)(out + (size_t)m * 256 + n0) = o;
        }
    }
}

// ---------- sampling: (b,h)-specialized blocks, XCD-pinned v-slices ----------
// Block = ONE (b,h) x 16 queries. xcd = blk&7 -> each XCD serves 4 fixed (b,h)
// combos; per-XCD v working set 2.2MB < 4MB L2.
// Phase A: thread t <-> (task = t>>4, p = t&15); softmax via 16-lane shfl;
// corner weights packed to f16x2 PAIRS. Phase B: level-balanced p = jj*4 +
// wp*2 + pgl; 16 hoisted 16B gathers; dot2 MAC. mid written FRAG-LINEAR
// (enables LDS-free gemm_o): one contiguous 16B store per lane.
__global__ void sample_kernel(
    const _Float16* __restrict__ v,          // [b][h][LV][32] fp16
    const float* __restrict__ oa,            // [NQ][384]: 0..255 offsets, 256..383 logits
    const float* __restrict__ refp,          // [NQ][4]
    _Float16* __restrict__ midf)             // frag-linear [NQ/16][8][512] fp16
{
    const int blk = blockIdx.x;
    const int xcd = blk & 7, j = blk >> 3;
    const int bh = xcd * 4 + (j & 3);        // 0..31
    const int chunk = j >> 2;                // 0..255
    const int b = bh >> 3, h = bh & 7;
    const int rowG0 = b * LQ + chunk * 16;

    const int t = threadIdx.x;
    const int wave = t >> 6, lane = t & 63;

    __shared__ __align__(16) int2   s_pk[16 * 17];      // 2176 B
    __shared__ __align__(16) int2   s_w2[16 * 17];      // 2176 B (f16x2 pairs)
    __shared__ __align__(16) float  s_part[2 * 8 * 32]; // 2048 B

    // --- Phase A: logits+offsets -> softmax (shfl) -> corner descriptors ---
    {
        int task = t >> 4, p = t & 15, l = p >> 2;
        int row = rowG0 + task;
        float4 r4 = *(const float4*)(refp + (size_t)row * 4);
        float2 o2 = *(const float2*)(oa + (size_t)row * 384 + (h * 16 + p) * 2);
        float raw = oa[(size_t)row * 384 + 256 + h * 16 + p];

        // softmax over the 16 p-lanes of this task (16-lane aligned group)
        float mx = raw;
        #pragma unroll
        for (int d = 8; d >= 1; d >>= 1) mx = fmaxf(mx, __shfl_xor(mx, d, 16));
        float ex = __expf(raw - mx);
        float sm = ex;
        #pragma unroll
        for (int d = 8; d >= 1; d >>= 1) sm += __shfl_xor(sm, d, 16);
        float w = ex * __builtin_amdgcn_rcpf(sm);

        int Wl = 80 >> l;
        int vst = (l == 0) ? 0 : (l == 1) ? 6400 : (l == 2) ? 8000 : 8400;
        float x = (r4.x + o2.x * 0.125f * r4.z) * Wl - 0.5f;
        float y = (r4.y + o2.y * 0.125f * r4.w) * Wl - 0.5f;
        float x0f = floorf(x), y0f = floorf(y);
        float lx = x - x0f, ly = y - y0f;
        int x0 = (int)x0f, y0 = (int)y0f;
        int x1 = x0 + 1, y1 = y0 + 1;
        float mx0 = (x0 >= 0 && x0 < Wl) ? 1.f : 0.f;
        float mx1 = (x1 >= 0 && x1 < Wl) ? 1.f : 0.f;
        float my0 = (y0 >= 0 && y0 < Wl) ? 1.f : 0.f;
        float my1 = (y1 >= 0 && y1 < Wl) ? 1.f : 0.f;
        int cx0 = min(max(x0, 0), Wl - 1), cx1 = min(max(x1, 0), Wl - 1);
        int cy0 = min(max(y0, 0), Wl - 1), cy1 = min(max(y1, 0), Wl - 1);
        int2 r_pk;
        r_pk.x = (vst + cy0 * Wl + cx0) * 64;
        r_pk.y = ((cx1 - cx0) * 64) | (((cy1 - cy0) * Wl * 64) << 16);
        f16x2 wxy, wzw;
        wxy[0] = (_Float16)(w * (1.f - lx) * (1.f - ly) * mx0 * my0);
        wxy[1] = (_Float16)(w * lx * (1.f - ly) * mx1 * my0);
        wzw[0] = (_Float16)(w * (1.f - lx) * ly * mx0 * my1);
        wzw[1] = (_Float16)(w * lx * ly * mx1 * my1);
        int2 r_w2;
        r_w2.x = __builtin_bit_cast(int, wxy);
        r_w2.y = __builtin_bit_cast(int, wzw);
        int s = task * 17 + p;
        s_pk[s] = r_pk; s_w2[s] = r_w2;
    }
    __syncthreads();

    // --- Phase B: gather with all 16 loads hoisted, dot2 MAC ---
    {
        const int wg = wave >> 1, wp = wave & 1;
        const int pgl = lane >> 5, tk = (lane >> 2) & 7, dv2 = lane & 3;
        const int task = wg * 8 + tk;
        const int row = rowG0 + task;
        const char* vb = (const char*)v + ((size_t)(b * NH + h) * LV) * 64 + dv2 * 16;

        int2 pk[4]; f16x2 wxy[4], wzw[4];
        #pragma unroll
        for (int jj = 0; jj < 4; ++jj) {
            int p = jj * 4 + wp * 2 + pgl;       // one point per level per jj
            int s = task * 17 + p;
            pk[jj] = s_pk[s];
            int2 w2 = s_w2[s];
            wxy[jj] = __builtin_bit_cast(f16x2, w2.x);
            wzw[jj] = __builtin_bit_cast(f16x2, w2.y);
        }
        f16x8 g0[4], g1[4], g2[4], g3[4];
        #pragma unroll
        for (int jj = 0; jj < 4; ++jj) {
            int dx = pk[jj].y & 0xffff, dy = pk[jj].y >> 16;
            const char* base = vb + pk[jj].x;
            g0[jj] = *(const f16x8*)(base);
            g1[jj] = *(const f16x8*)(base + dx);
            g2[jj] = *(const f16x8*)(base + dy);
            g3[jj] = *(const f16x8*)(base + dx + dy);
        }
        float acc8[8] = {};
        #pragma unroll
        for (int jj = 0; jj < 4; ++jj)
            #pragma unroll
            for (int c = 0; c < 8; ++c) {
                f16x2 ga; ga[0] = g0[jj][c]; ga[1] = g1[jj][c];
                f16x2 gb; gb[0] = g2[jj][c]; gb[1] = g3[jj][c];
                acc8[c] = __builtin_amdgcn_fdot2(ga, wxy[jj], acc8[c], false);
                acc8[c] = __builtin_amdgcn_fdot2(gb, wzw[jj], acc8[c], false);
            }

        // combine pgl halves within wave
        #pragma unroll
        for (int c = 0; c < 8; ++c) acc8[c] += __shfl_xor(acc8[c], 32, 64);
        // cross-wave combine via LDS (dword-transposed: conflict-free)
        if (wp == 1 && lane < 32) {
            #pragma unroll
            for (int c = 0; c < 8; ++c) s_part[wg * 256 + c * 32 + lane] = acc8[c];
        }
        __syncthreads();
        if (wp == 0 && lane < 32) {
            f16x8 m8;
            #pragma unroll
            for (int c = 0; c < 8; ++c)
                m8[c] = (_Float16)(acc8[c] + s_part[wg * 256 + c * 32 + lane]);
            // frag-linear store: T=row>>4, C=h, lane16=(row&15)+16*dv2
            *(f16x8*)(midf + ((size_t)(row >> 4) * 8 + h) * 512
                           + ((row & 15) + 16 * dv2) * 8) = m8;
        }
    }
}

extern "C" void kernel_launch(void* const* d_in, const int* in_sizes, int n_in,
                              void* d_out, int out_size, void* d_ws, size_t ws_size,
                              hipStream_t stream) {
    const float* query  = (const float*)d_in[0];   // [4,4096,256]
    const float* refp   = (const float*)d_in[1];   // [4,4096,1,4]
    const float* value  = (const float*)d_in[2];   // [4,8500,256]
    const float* W_off  = (const float*)d_in[3];   // [256,256]
    const float* b_off  = (const float*)d_in[4];   // [256]
    const float* W_attn = (const float*)d_in[5];   // [256,128]
    const float* b_attn = (const float*)d_in[6];   // [128]
    const float* W_v    = (const float*)d_in[7];   // [256,256]
    const float* b_v    = (const float*)d_in[8];   // [256]
    const float* W_o    = (const float*)d_in[9];   // [256,256]
    const float* b_o    = (const float*)d_in[10];  // [256]

    char* ws = (char*)d_ws;
    _Float16* v_f16  = (_Float16*)(ws + 0);               // 17,408,000 B
    float*    oa_f32 = (float*)(ws + 17408000);           // 25,165,824 B
    _Float16* mid    = (_Float16*)(ws + 42573824);        //  8,388,608 B (frag-linear)
    _Float16* WtVf   = (_Float16*)(ws + 50962432);        //    131,072 B
    _Float16* WtOAf  = (_Float16*)(ws + 51093504);        //    196,608 B
    _Float16* WtOf   = (_Float16*)(ws + 51290112);        //    131,072 B
    float*    biasOA = (float*)(ws + 51421184);           //      1,536 B

    prep_kernel<<<896, 256, 0, stream>>>(W_v, W_off, W_attn, W_o, b_off, b_attn,
                                         WtVf, WtOAf, WtOf, biasOA);
    gemm_dual_kernel<<<1044, 256, 0, stream>>>(
        value, WtVf, b_v, v_f16, query, WtOAf, biasOA, oa_f32);
    sample_kernel<<<8192, 256, 0, stream>>>(v_f16, oa_f32, refp, mid);
    gemm_o_kernel<<<1024, 256, 0, stream>>>(mid, WtOf, b_o, (float*)d_out);
}